// Round 1
// baseline (1681.988 us; speedup 1.0000x reference)
//
#include <hip/hip_runtime.h>
#include <math.h>

#define KDIM 65536
#define MATF 262144           // 512*512 floats
#define NK 16
#define CHUNK 4096            // KDIM/NK
#define GEPS 1e-6f

// ---- ws layout (bytes) ----
// 0      : float M[1024]            (input rows 0..511, target rows 512..1023)
// 4096   : double S[16]             (0:n2A 1:n2B 2:trA 3:trB 4:cross)
// 8192   : float G[2*MATF]                                   (2 MB)
// +2MB   : Y0[2*MATF] Y1[2*MATF] Z0[2*MATF] Z1[2*MATF] T[2*MATF]  (10 MB)
// +12MB  : float Gp[2*NK*MATF]      split-K gram partials    (32 MB)

__global__ __launch_bounds__(256) void k_means(const float* __restrict__ X,
                                               const float* __restrict__ Xt,
                                               float* __restrict__ M) {
  const int row = blockIdx.x, inp = blockIdx.y;
  const float4* p = (const float4*)((inp ? Xt : X) + (size_t)row * KDIM);
  double s = 0.0;
  for (int i = threadIdx.x; i < KDIM / 4; i += 256) {
    float4 v = p[i];
    s += (double)v.x + (double)v.y + (double)v.z + (double)v.w;
  }
  __shared__ double sm[256];
  sm[threadIdx.x] = s;
  __syncthreads();
  for (int o = 128; o > 0; o >>= 1) {
    if (threadIdx.x < o) sm[threadIdx.x] += sm[threadIdx.x + o];
    __syncthreads();
  }
  if (threadIdx.x == 0) M[inp * 512 + row] = (float)(sm[0] * (1.0 / KDIM));
}

// Gram split-K: grid (36 upper-tri tiles, NK chunks, 2 inputs), 256 thr.
// Tile 64x64, BK=32, 4x4 microtile. Deterministic partials, no atomics.
__global__ __launch_bounds__(256) void k_gram(const float* __restrict__ X,
                                              const float* __restrict__ Xt,
                                              const float* __restrict__ M,
                                              float* __restrict__ Gp) {
  const int chunk = blockIdx.y, inp = blockIdx.z;
  int rem = blockIdx.x, ti = 0;
  while (rem >= 8 - ti) { rem -= 8 - ti; ++ti; }
  const int tj = ti + rem;

  const float* __restrict__ A = inp ? Xt : X;
  const float* __restrict__ Mr = M + inp * 512;
  float* __restrict__ C = Gp + ((size_t)(inp * NK + chunk)) * MATF;

  __shared__ __align__(16) float As[32][68];
  __shared__ __align__(16) float Bs[32][68];

  const int t = threadIdx.x;
  const int tx = t & 15, ty = t >> 4;   // tx: col group, ty: row group
  const int li = t >> 3;                // 0..31 staging row
  const int lk = (t & 7) << 2;          // 0,4,..,28 staging k

  const float mA0 = Mr[ti * 64 + li];
  const float mA1 = Mr[ti * 64 + li + 32];
  const float mB0 = Mr[tj * 64 + li];
  const float mB1 = Mr[tj * 64 + li + 32];

  const float* pa0 = A + (size_t)(ti * 64 + li) * KDIM + (size_t)chunk * CHUNK + lk;
  const float* pa1 = pa0 + (size_t)32 * KDIM;
  const float* pb0 = A + (size_t)(tj * 64 + li) * KDIM + (size_t)chunk * CHUNK + lk;
  const float* pb1 = pb0 + (size_t)32 * KDIM;

  float acc[4][4] = {};

  for (int ks = 0; ks < CHUNK; ks += 32) {
    float4 a0 = *(const float4*)(pa0 + ks);
    float4 a1 = *(const float4*)(pa1 + ks);
    float4 b0 = *(const float4*)(pb0 + ks);
    float4 b1 = *(const float4*)(pb1 + ks);
    As[lk + 0][li] = a0.x - mA0; As[lk + 1][li] = a0.y - mA0;
    As[lk + 2][li] = a0.z - mA0; As[lk + 3][li] = a0.w - mA0;
    As[lk + 0][li + 32] = a1.x - mA1; As[lk + 1][li + 32] = a1.y - mA1;
    As[lk + 2][li + 32] = a1.z - mA1; As[lk + 3][li + 32] = a1.w - mA1;
    Bs[lk + 0][li] = b0.x - mB0; Bs[lk + 1][li] = b0.y - mB0;
    Bs[lk + 2][li] = b0.z - mB0; Bs[lk + 3][li] = b0.w - mB0;
    Bs[lk + 0][li + 32] = b1.x - mB1; Bs[lk + 1][li + 32] = b1.y - mB1;
    Bs[lk + 2][li + 32] = b1.z - mB1; Bs[lk + 3][li + 32] = b1.w - mB1;
    __syncthreads();
#pragma unroll
    for (int kk = 0; kk < 32; ++kk) {
      const float4 av = *(const float4*)&As[kk][ty << 2];
      const float4 bv = *(const float4*)&Bs[kk][tx << 2];
      acc[0][0] += av.x * bv.x; acc[0][1] += av.x * bv.y; acc[0][2] += av.x * bv.z; acc[0][3] += av.x * bv.w;
      acc[1][0] += av.y * bv.x; acc[1][1] += av.y * bv.y; acc[1][2] += av.y * bv.z; acc[1][3] += av.y * bv.w;
      acc[2][0] += av.z * bv.x; acc[2][1] += av.z * bv.y; acc[2][2] += av.z * bv.z; acc[2][3] += av.z * bv.w;
      acc[3][0] += av.w * bv.x; acc[3][1] += av.w * bv.y; acc[3][2] += av.w * bv.z; acc[3][3] += av.w * bv.w;
    }
    __syncthreads();
  }
#pragma unroll
  for (int r = 0; r < 4; ++r) {
    float4 v = make_float4(acc[r][0], acc[r][1], acc[r][2], acc[r][3]);
    *(float4*)&C[(size_t)(ti * 64 + (ty << 2) + r) * 512 + tj * 64 + (tx << 2)] = v;
  }
}

// Reduce split-K partials (fp64), finalize G (sym mirror), accumulate
// Frobenius^2 and trace in fp64.
__global__ __launch_bounds__(256) void k_gfin(const float* __restrict__ Gp,
                                              float* __restrict__ G,
                                              double* __restrict__ S) {
  const int inp = blockIdx.y;
  const int idx = blockIdx.x * 256 + threadIdx.x;
  const int i = idx >> 9, j = idx & 511;
  double n2 = 0.0, tr = 0.0;
  float* g = G + (size_t)inp * MATF;
  if (i <= j) {
    double sum = 0.0;
    const float* p = Gp + (size_t)inp * NK * MATF + idx;
#pragma unroll
    for (int c = 0; c < NK; ++c) sum += (double)p[(size_t)c * MATF];
    if (i == j) sum += (double)GEPS;
    float v = (float)(sum * (1.0 / 65536.0));
    g[idx] = v;
    if (i < j) { g[(size_t)j * 512 + i] = v; n2 = 2.0 * (double)v * (double)v; }
    else       { n2 = (double)v * (double)v; tr = (double)v; }
  }
  __shared__ double s1[256], s2[256];
  s1[threadIdx.x] = n2; s2[threadIdx.x] = tr;
  __syncthreads();
  for (int o = 128; o > 0; o >>= 1) {
    if (threadIdx.x < o) { s1[threadIdx.x] += s1[threadIdx.x + o]; s2[threadIdx.x] += s2[threadIdx.x + o]; }
    __syncthreads();
  }
  if (threadIdx.x == 0) { atomicAdd(&S[inp], s1[0]); atomicAdd(&S[2 + inp], s2[0]); }
}

__global__ __launch_bounds__(256) void k_nsinit(const float* __restrict__ G,
                                                float* __restrict__ Y,
                                                float* __restrict__ Z,
                                                const double* __restrict__ S) {
  const int inp = blockIdx.y;
  const int idx = blockIdx.x * 256 + threadIdx.x;
  const float norm = (float)sqrt(S[inp]);
  const size_t o = (size_t)inp * MATF + idx;
  Y[o] = G[o] / norm;
  Z[o] = ((idx >> 9) == (idx & 511)) ? 1.0f : 0.0f;
}

// 512^3 fp32 GEMM tile: 64x64 tile, BK=32, 4x4 microtile.
__device__ __forceinline__ void gemm512(const float* __restrict__ A,
                                        const float* __restrict__ B,
                                        float* __restrict__ C, int affine) {
  __shared__ __align__(16) float As[32][68];
  __shared__ __align__(16) float Bs[32][68];
  const int t = threadIdx.x;
  const int tx = t & 15, ty = t >> 4;
  const int bi = blockIdx.x, bj = blockIdx.y;
  const int li = t >> 3, lk = (t & 7) << 2;
  const int bkk = t >> 4, bj4 = (t & 15) << 2;

  const float* pa0 = A + (size_t)(bi * 64 + li) * 512 + lk;
  const float* pa1 = pa0 + 32 * 512;
  const float* pb0 = B + (size_t)bkk * 512 + bj * 64 + bj4;
  const float* pb1 = pb0 + 16 * 512;

  float acc[4][4] = {};
  for (int k0 = 0; k0 < 512; k0 += 32) {
    float4 a0 = *(const float4*)(pa0 + k0);
    float4 a1 = *(const float4*)(pa1 + k0);
    float4 b0 = *(const float4*)(pb0 + (size_t)k0 * 512);
    float4 b1 = *(const float4*)(pb1 + (size_t)k0 * 512);
    As[lk + 0][li] = a0.x; As[lk + 1][li] = a0.y; As[lk + 2][li] = a0.z; As[lk + 3][li] = a0.w;
    As[lk + 0][li + 32] = a1.x; As[lk + 1][li + 32] = a1.y; As[lk + 2][li + 32] = a1.z; As[lk + 3][li + 32] = a1.w;
    *(float4*)&Bs[bkk][bj4] = b0;
    *(float4*)&Bs[bkk + 16][bj4] = b1;
    __syncthreads();
#pragma unroll
    for (int kk = 0; kk < 32; ++kk) {
      const float4 av = *(const float4*)&As[kk][ty << 2];
      const float4 bv = *(const float4*)&Bs[kk][tx << 2];
      acc[0][0] += av.x * bv.x; acc[0][1] += av.x * bv.y; acc[0][2] += av.x * bv.z; acc[0][3] += av.x * bv.w;
      acc[1][0] += av.y * bv.x; acc[1][1] += av.y * bv.y; acc[1][2] += av.y * bv.z; acc[1][3] += av.y * bv.w;
      acc[2][0] += av.z * bv.x; acc[2][1] += av.z * bv.y; acc[2][2] += av.z * bv.z; acc[2][3] += av.z * bv.w;
      acc[3][0] += av.w * bv.x; acc[3][1] += av.w * bv.y; acc[3][2] += av.w * bv.z; acc[3][3] += av.w * bv.w;
    }
    __syncthreads();
  }
#pragma unroll
  for (int r = 0; r < 4; ++r) {
    const int gi = bi * 64 + (ty << 2) + r;
    float4 v = make_float4(acc[r][0], acc[r][1], acc[r][2], acc[r][3]);
    if (affine) {
      const int gj0 = bj * 64 + (tx << 2);
      v.x = 0.5f * ((gi == gj0 + 0 ? 3.0f : 0.0f) - v.x);
      v.y = 0.5f * ((gi == gj0 + 1 ? 3.0f : 0.0f) - v.y);
      v.z = 0.5f * ((gi == gj0 + 2 ? 3.0f : 0.0f) - v.z);
      v.w = 0.5f * ((gi == gj0 + 3 ? 3.0f : 0.0f) - v.w);
    }
    *(float4*)&C[(size_t)gi * 512 + bj * 64 + (tx << 2)] = v;
  }
}

// T = 0.5*(3I - Z@Y), batched over 2 matrices. grid (8,8,2)
__global__ __launch_bounds__(256) void k_ns_T(const float* __restrict__ Y,
                                              const float* __restrict__ Z,
                                              float* __restrict__ T) {
  const size_t o = (size_t)blockIdx.z * MATF;
  gemm512(Z + o, Y + o, T + o, 1);
}

// Yn = Y@T ; Zn = T@Z, batched over 2 matrices. grid (8,8,4)
__global__ __launch_bounds__(256) void k_ns_YZ(const float* __restrict__ Y,
                                               const float* __restrict__ Z,
                                               const float* __restrict__ T,
                                               float* __restrict__ Yn,
                                               float* __restrict__ Zn) {
  const int z = blockIdx.z;
  const size_t o = (size_t)(z >> 1) * MATF;
  const float *Aa, *Bb;
  float* Cc;
  if ((z & 1) == 0) { Aa = Y + o; Bb = T + o; Cc = Yn + o; }
  else              { Aa = T + o; Bb = Z + o; Cc = Zn + o; }
  gemm512(Aa, Bb, Cc, 0);
}

// cross = sum_ij YA[i,j]*YB[j,i] in fp64. grid 256.
__global__ __launch_bounds__(256) void k_cross(const float* __restrict__ YA,
                                               const float* __restrict__ YB,
                                               double* __restrict__ S) {
  const int base = (blockIdx.x * 256 + threadIdx.x) * 4;
  double s = 0.0;
#pragma unroll
  for (int r = 0; r < 4; ++r) {
    const int id = base + r;
    const int i = id >> 9, j = id & 511;
    s += (double)YA[id] * (double)YB[j * 512 + i];
  }
  __shared__ double sm[256];
  sm[threadIdx.x] = s;
  __syncthreads();
  for (int o = 128; o > 0; o >>= 1) {
    if (threadIdx.x < o) sm[threadIdx.x] += sm[threadIdx.x + o];
    __syncthreads();
  }
  if (threadIdx.x == 0) atomicAdd(&S[4], sm[0]);
}

__global__ __launch_bounds__(256) void k_final(const float* __restrict__ M,
                                               const double* __restrict__ S,
                                               float* __restrict__ out) {
  double s = 0.0;
  for (int i = threadIdx.x; i < 512; i += 256) {
    double d = (double)M[i] - (double)M[512 + i];
    s += d * d;
  }
  __shared__ double sm[256];
  sm[threadIdx.x] = s;
  __syncthreads();
  for (int o = 128; o > 0; o >>= 1) {
    if (threadIdx.x < o) sm[threadIdx.x] += sm[threadIdx.x + o];
    __syncthreads();
  }
  if (threadIdx.x == 0) {
    double scale = sqrt(sqrt(S[0]) * sqrt(S[1]));   // sqrt(normA)*sqrt(normB)
    double loss = sm[0] + S[2] + S[3] - 2.0 * scale * S[4];
    out[0] = (float)(loss / 512.0);
  }
}

extern "C" void kernel_launch(void* const* d_in, const int* in_sizes, int n_in,
                              void* d_out, int out_size, void* d_ws, size_t ws_size,
                              hipStream_t stream) {
  const float* X = (const float*)d_in[0];
  const float* Xt = (const float*)d_in[1];
  char* wsb = (char*)d_ws;
  float* Mv = (float*)wsb;
  double* S = (double*)(wsb + 4096);
  float* mats = (float*)(wsb + 8192);
  float* G = mats;
  float* Y[2] = { mats + 2 * (size_t)MATF, mats + 4 * (size_t)MATF };
  float* Z[2] = { mats + 6 * (size_t)MATF, mats + 8 * (size_t)MATF };
  float* T = mats + 10 * (size_t)MATF;
  float* Gp = mats + 12 * (size_t)MATF;

  hipMemsetAsync(S, 0, 16 * sizeof(double), stream);
  k_means<<<dim3(512, 2), 256, 0, stream>>>(X, Xt, Mv);
  k_gram<<<dim3(36, NK, 2), 256, 0, stream>>>(X, Xt, Mv, Gp);
  k_gfin<<<dim3(1024, 2), 256, 0, stream>>>(Gp, G, S);
  k_nsinit<<<dim3(1024, 2), 256, 0, stream>>>(G, Y[0], Z[0], S);
  int cur = 0;
  for (int it = 0; it < 15; ++it) {
    k_ns_T<<<dim3(8, 8, 2), 256, 0, stream>>>(Y[cur], Z[cur], T);
    k_ns_YZ<<<dim3(8, 8, 4), 256, 0, stream>>>(Y[cur], Z[cur], T, Y[1 - cur], Z[1 - cur]);
    cur ^= 1;
  }
  k_cross<<<dim3(256), 256, 0, stream>>>(Y[cur], Y[cur] + MATF, S);
  k_final<<<dim3(1), 256, 0, stream>>>(Mv, S, (float*)d_out);
}

// Round 2
// 1416.239 us; speedup vs baseline: 1.1876x; 1.1876x over previous
//
#include <hip/hip_runtime.h>
#include <math.h>

#define KDIM 65536
#define MATF 262144           // 512*512 floats
#define NK 16
#define CHUNK 4096            // KDIM/NK
#define EPSG 1e-6

using bf16x8 = __attribute__((ext_vector_type(8))) __bf16;
using f32x4  = __attribute__((ext_vector_type(4))) float;

// ---- ws layout ----
// 0      : float M[1024]
// 4096   : double S[16]   (0:n2A 1:n2B 2:trA 3:trB 4:cross)
// 8192   : float G[2*MATF]                       (2 MB)
// 8192+2M: "big" region, 32 MB:
//          Gp[2*NK*MATF] split-K gram partials (dead after k_gfin)
//          then reused: Yb0(4M) Yb1(4M) Zb0(4M) Zb1(4M) W(4M)
//          each NS matrix = 2 mats x 2 K-partials of 1 MB

__global__ __launch_bounds__(256) void k_means(const float* __restrict__ X,
                                               const float* __restrict__ Xt,
                                               float* __restrict__ M) {
  const int row = blockIdx.x, inp = blockIdx.y;
  const float4* p = (const float4*)((inp ? Xt : X) + (size_t)row * KDIM);
  double s = 0.0;
  for (int i = threadIdx.x; i < KDIM / 4; i += 256) {
    float4 v = p[i];
    s += (double)v.x + (double)v.y + (double)v.z + (double)v.w;
  }
  __shared__ double sm[256];
  sm[threadIdx.x] = s;
  __syncthreads();
  for (int o = 128; o > 0; o >>= 1) {
    if (threadIdx.x < o) sm[threadIdx.x] += sm[threadIdx.x + o];
    __syncthreads();
  }
  if (threadIdx.x == 0) M[inp * 512 + row] = (float)(sm[0] * (1.0 / KDIM));
}

__device__ __forceinline__ void cvt8(float4 a, float4 b, bf16x8& hi, bf16x8& lo) {
  float f[8] = {a.x, a.y, a.z, a.w, b.x, b.y, b.z, b.w};
#pragma unroll
  for (int e = 0; e < 8; ++e) {
    __bf16 h = (__bf16)f[e];
    hi[e] = h;
    lo[e] = (__bf16)(f[e] - (float)h);
  }
}

// Raw X X^T partials via bf16 split-3 MFMA. 128x128 tiles (upper tri, 10),
// split-K NK chunks. grid (10, NK, 2), 256 threads.
// LDS frag-ordered: slot(row,k) = (row>>4)*64 + (k>>3)*16 + (row&15), bf16x8
// per slot -> frag reads are lane-contiguous 16B (conflict-free).
__global__ __launch_bounds__(256, 2) void k_gram(const float* __restrict__ X,
                                                 const float* __restrict__ Xt,
                                                 float* __restrict__ Gp) {
  int rem = blockIdx.x, ti = 0;
  while (rem >= 4 - ti) { rem -= 4 - ti; ++ti; }
  const int tj = ti + rem;
  const int chunk = blockIdx.y, inp = blockIdx.z;
  const float* __restrict__ A = inp ? Xt : X;
  float* __restrict__ C = Gp + ((size_t)(inp * NK + chunk)) * MATF;
  const bool diag = (ti == tj);

  __shared__ bf16x8 AhV[512], AlV[512], BhV[512], BlV[512];   // 8 KB each

  const int t = threadIdx.x;
  const int srow = t & 127, skh = t >> 7;                 // stage row, k-half
  const int sbase = ((srow >> 4) << 6) + (skh << 5) + (srow & 15);

  const float* pa = A + (size_t)(ti * 128 + srow) * KDIM + (size_t)chunk * CHUNK + skh * 16;
  const float* pb = A + (size_t)(tj * 128 + srow) * KDIM + (size_t)chunk * CHUNK + skh * 16;

  const int wave = t >> 6, lane = t & 63;
  const int wy = (wave >> 1) * 64, wx = (wave & 1) * 64;

  f32x4 acc[4][4];
#pragma unroll
  for (int i = 0; i < 4; ++i)
#pragma unroll
    for (int j = 0; j < 4; ++j) acc[i][j] = (f32x4){0.f, 0.f, 0.f, 0.f};

  for (int ks = 0; ks < CHUNK; ks += 32) {
    {
      float4 v0 = *(const float4*)(pa + ks);
      float4 v1 = *(const float4*)(pa + ks + 4);
      float4 v2 = *(const float4*)(pa + ks + 8);
      float4 v3 = *(const float4*)(pa + ks + 12);
      bf16x8 h, l;
      cvt8(v0, v1, h, l); AhV[sbase] = h; AlV[sbase] = l;
      cvt8(v2, v3, h, l); AhV[sbase + 16] = h; AlV[sbase + 16] = l;
      if (!diag) {
        v0 = *(const float4*)(pb + ks);
        v1 = *(const float4*)(pb + ks + 4);
        v2 = *(const float4*)(pb + ks + 8);
        v3 = *(const float4*)(pb + ks + 12);
        cvt8(v0, v1, h, l); BhV[sbase] = h; BlV[sbase] = l;
        cvt8(v2, v3, h, l); BhV[sbase + 16] = h; BlV[sbase + 16] = l;
      }
    }
    __syncthreads();
    const bf16x8* __restrict__ Bh = diag ? AhV : BhV;
    const bf16x8* __restrict__ Bl = diag ? AlV : BlV;
    bf16x8 ah[4], al[4], bh[4], bl[4];
#pragma unroll
    for (int g = 0; g < 4; ++g) {
      ah[g] = AhV[((wave >> 1) * 4 + g) * 64 + lane];
      al[g] = AlV[((wave >> 1) * 4 + g) * 64 + lane];
      bh[g] = Bh[((wave & 1) * 4 + g) * 64 + lane];
      bl[g] = Bl[((wave & 1) * 4 + g) * 64 + lane];
    }
#pragma unroll
    for (int i = 0; i < 4; ++i)
#pragma unroll
      for (int j = 0; j < 4; ++j) {
        acc[i][j] = __builtin_amdgcn_mfma_f32_16x16x32_bf16(ah[i], bh[j], acc[i][j], 0, 0, 0);
        acc[i][j] = __builtin_amdgcn_mfma_f32_16x16x32_bf16(al[i], bh[j], acc[i][j], 0, 0, 0);
        acc[i][j] = __builtin_amdgcn_mfma_f32_16x16x32_bf16(ah[i], bl[j], acc[i][j], 0, 0, 0);
      }
    __syncthreads();
  }
  const int r4 = (lane >> 4) * 4, fc = lane & 15;
#pragma unroll
  for (int i = 0; i < 4; ++i) {
    const int grow = ti * 128 + wy + i * 16 + r4;
#pragma unroll
    for (int j = 0; j < 4; ++j) {
      const int gcol = tj * 128 + wx + j * 16 + fc;
#pragma unroll
      for (int r = 0; r < 4; ++r)
        C[(size_t)(grow + r) * 512 + gcol] = acc[i][j][r];
    }
  }
}

// Reduce NK partials (fp64), apply mean correction -K*mi*mj + eps, /K.
// Mirror to lower tri; accumulate ||G||_F^2 and trace.
__global__ __launch_bounds__(256) void k_gfin(const float* __restrict__ Gp,
                                              const float* __restrict__ M,
                                              float* __restrict__ G,
                                              double* __restrict__ S) {
  const int inp = blockIdx.y;
  const int idx = blockIdx.x * 256 + threadIdx.x;
  const int i = idx >> 9, j = idx & 511;
  double n2 = 0.0, tr = 0.0;
  float* g = G + (size_t)inp * MATF;
  if (i <= j) {
    double sum = 0.0;
    const float* p = Gp + (size_t)inp * NK * MATF + idx;
#pragma unroll
    for (int c = 0; c < NK; ++c) sum += (double)p[(size_t)c * MATF];
    sum -= 65536.0 * (double)M[inp * 512 + i] * (double)M[inp * 512 + j];
    if (i == j) sum += EPSG;
    float v = (float)(sum * (1.0 / 65536.0));
    g[idx] = v;
    if (i < j) { g[(size_t)j * 512 + i] = v; n2 = 2.0 * (double)v * (double)v; }
    else       { n2 = (double)v * (double)v; tr = (double)v; }
  }
  __shared__ double s1[256], s2[256];
  s1[threadIdx.x] = n2; s2[threadIdx.x] = tr;
  __syncthreads();
  for (int o = 128; o > 0; o >>= 1) {
    if (threadIdx.x < o) { s1[threadIdx.x] += s1[threadIdx.x + o]; s2[threadIdx.x] += s2[threadIdx.x + o]; }
    __syncthreads();
  }
  if (threadIdx.x == 0) { atomicAdd(&S[inp], s1[0]); atomicAdd(&S[2 + inp], s2[0]); }
}

// Y/Z stored as 2 K-partials each (summed on read). Init: p0=value, p1=0.
__global__ __launch_bounds__(256) void k_nsinit(const float* __restrict__ G,
                                                float* __restrict__ Y,
                                                float* __restrict__ Z,
                                                const double* __restrict__ S) {
  const int inp = blockIdx.y;
  const int idx = blockIdx.x * 256 + threadIdx.x;
  const float norm = (float)sqrt(S[inp]);
  Y[(size_t)(inp * 2 + 0) * MATF + idx] = G[(size_t)inp * MATF + idx] / norm;
  Y[(size_t)(inp * 2 + 1) * MATF + idx] = 0.0f;
  Z[(size_t)(inp * 2 + 0) * MATF + idx] = ((idx >> 9) == (idx & 511)) ? 1.0f : 0.0f;
  Z[(size_t)(inp * 2 + 1) * MATF + idx] = 0.0f;
}

// 64x64-tile fp32 GEMM over K range [k0,k0+256), operands = sum of 2 partials.
// mode 0: C = acc; mode 1: C = 1.5*(E0+E1) - 0.5*acc; mode 2: C = -0.5*acc
__device__ __forceinline__ void gemm_ns(const float* __restrict__ A0, const float* __restrict__ A1,
                                        const float* __restrict__ B0, const float* __restrict__ B1,
                                        const float* __restrict__ E0, const float* __restrict__ E1,
                                        float* __restrict__ C, int k0, int mode) {
  __shared__ __align__(16) float As[64][68];   // [k][row]
  __shared__ __align__(16) float Bs[64][68];   // [k][col]
  const int t = threadIdx.x;
  const int tx = t & 15, ty = t >> 4;
  const int bi = blockIdx.x, bj = blockIdx.y;
  const int ar = t & 63, akq = t >> 6;          // A stage: row, k-quarter
  const int bkr = t >> 2, bcs = (t & 3) * 16;   // B stage: k-row, col-seg

  const float* pa0 = A0 + (size_t)(bi * 64 + ar) * 512 + k0 + akq * 16;
  const float* pa1 = A1 + (size_t)(bi * 64 + ar) * 512 + k0 + akq * 16;
  const float* pb0 = B0 + (size_t)(k0 + bkr) * 512 + bj * 64 + bcs;
  const float* pb1 = B1 + (size_t)(k0 + bkr) * 512 + bj * 64 + bcs;

  float acc[4][4] = {};
  for (int ks = 0; ks < 256; ks += 64) {
#pragma unroll
    for (int q = 0; q < 4; ++q) {
      float4 va = *(const float4*)(pa0 + ks + q * 4);
      float4 vb = *(const float4*)(pa1 + ks + q * 4);
      const int kk = akq * 16 + q * 4;
      As[kk + 0][ar] = va.x + vb.x; As[kk + 1][ar] = va.y + vb.y;
      As[kk + 2][ar] = va.z + vb.z; As[kk + 3][ar] = va.w + vb.w;
    }
#pragma unroll
    for (int q = 0; q < 4; ++q) {
      float4 va = *(const float4*)(pb0 + (size_t)ks * 512 + q * 4);
      float4 vb = *(const float4*)(pb1 + (size_t)ks * 512 + q * 4);
      va.x += vb.x; va.y += vb.y; va.z += vb.z; va.w += vb.w;
      *(float4*)&Bs[bkr][bcs + q * 4] = va;
    }
    __syncthreads();
#pragma unroll 16
    for (int kk = 0; kk < 64; ++kk) {
      const float4 av = *(const float4*)&As[kk][ty << 2];
      const float4 bv = *(const float4*)&Bs[kk][tx << 2];
      acc[0][0] += av.x * bv.x; acc[0][1] += av.x * bv.y; acc[0][2] += av.x * bv.z; acc[0][3] += av.x * bv.w;
      acc[1][0] += av.y * bv.x; acc[1][1] += av.y * bv.y; acc[1][2] += av.y * bv.z; acc[1][3] += av.y * bv.w;
      acc[2][0] += av.z * bv.x; acc[2][1] += av.z * bv.y; acc[2][2] += av.z * bv.z; acc[2][3] += av.z * bv.w;
      acc[3][0] += av.w * bv.x; acc[3][1] += av.w * bv.y; acc[3][2] += av.w * bv.z; acc[3][3] += av.w * bv.w;
    }
    __syncthreads();
  }
#pragma unroll
  for (int r = 0; r < 4; ++r) {
    const int row = bi * 64 + (ty << 2) + r;
    const size_t off = (size_t)row * 512 + bj * 64 + (tx << 2);
    float4 v = make_float4(acc[r][0], acc[r][1], acc[r][2], acc[r][3]);
    if (mode != 0) {
      v.x *= -0.5f; v.y *= -0.5f; v.z *= -0.5f; v.w *= -0.5f;
      if (mode == 1) {
        float4 e0 = *(const float4*)(E0 + off);
        float4 e1 = *(const float4*)(E1 + off);
        v.x += 1.5f * (e0.x + e1.x); v.y += 1.5f * (e0.y + e1.y);
        v.z += 1.5f * (e0.z + e1.z); v.w += 1.5f * (e0.w + e1.w);
      }
    }
    *(float4*)&C[off] = v;
  }
}

// W = Z@Y as 2 K-partials, 2 matrices. grid (8,8,4): z = mat*2+part
__global__ __launch_bounds__(256) void k_ns_W(const float* __restrict__ Y,
                                              const float* __restrict__ Z,
                                              float* __restrict__ W) {
  const int mat = blockIdx.z >> 1, part = blockIdx.z & 1;
  const float* Zp = Z + (size_t)mat * 2 * MATF;
  const float* Yp = Y + (size_t)mat * 2 * MATF;
  gemm_ns(Zp, Zp + MATF, Yp, Yp + MATF, Yp, Yp,
          W + (size_t)(mat * 2 + part) * MATF, part * 256, 0);
}

// Yn = 1.5Y - 0.5*Y@W ; Zn = 1.5Z - 0.5*W@Z. grid (8,8,8):
// z = mat*4 + which*2 + part
__global__ __launch_bounds__(256) void k_ns_YZ(const float* __restrict__ Y,
                                               const float* __restrict__ Z,
                                               const float* __restrict__ W,
                                               float* __restrict__ Yn,
                                               float* __restrict__ Zn) {
  const int mat = blockIdx.z >> 2, which = (blockIdx.z >> 1) & 1, part = blockIdx.z & 1;
  const float* Yp = Y + (size_t)mat * 2 * MATF;
  const float* Zp = Z + (size_t)mat * 2 * MATF;
  const float* Wp = W + (size_t)mat * 2 * MATF;
  const int mode = (part == 0) ? 1 : 2;
  const float *a0, *a1, *b0, *b1, *e0, *e1;
  float* c;
  if (which == 0) {
    a0 = Yp; a1 = Yp + MATF; b0 = Wp; b1 = Wp + MATF; e0 = Yp; e1 = Yp + MATF;
    c = Yn + (size_t)(mat * 2 + part) * MATF;
  } else {
    a0 = Wp; a1 = Wp + MATF; b0 = Zp; b1 = Zp + MATF; e0 = Zp; e1 = Zp + MATF;
    c = Zn + (size_t)(mat * 2 + part) * MATF;
  }
  gemm_ns(a0, a1, b0, b1, e0, e1, c, part * 256, mode);
}

// cross = sum_ij YA[i,j]*YB[j,i] in fp64 (partial-summed operands). grid 256.
__global__ __launch_bounds__(256) void k_cross(const float* __restrict__ Y,
                                               double* __restrict__ S) {
  const float* YA0 = Y;            const float* YA1 = Y + MATF;
  const float* YB0 = Y + 2 * MATF; const float* YB1 = Y + 3 * MATF;
  const int base = (blockIdx.x * 256 + threadIdx.x) * 4;
  double s = 0.0;
#pragma unroll
  for (int r = 0; r < 4; ++r) {
    const int id = base + r;
    const int i = id >> 9, j = id & 511;
    const int jd = j * 512 + i;
    s += ((double)YA0[id] + (double)YA1[id]) * ((double)YB0[jd] + (double)YB1[jd]);
  }
  __shared__ double sm[256];
  sm[threadIdx.x] = s;
  __syncthreads();
  for (int o = 128; o > 0; o >>= 1) {
    if (threadIdx.x < o) sm[threadIdx.x] += sm[threadIdx.x + o];
    __syncthreads();
  }
  if (threadIdx.x == 0) atomicAdd(&S[4], sm[0]);
}

__global__ __launch_bounds__(256) void k_final(const float* __restrict__ M,
                                               const double* __restrict__ S,
                                               float* __restrict__ out) {
  double s = 0.0;
  for (int i = threadIdx.x; i < 512; i += 256) {
    double d = (double)M[i] - (double)M[512 + i];
    s += d * d;
  }
  __shared__ double sm[256];
  sm[threadIdx.x] = s;
  __syncthreads();
  for (int o = 128; o > 0; o >>= 1) {
    if (threadIdx.x < o) sm[threadIdx.x] += sm[threadIdx.x + o];
    __syncthreads();
  }
  if (threadIdx.x == 0) {
    double scale = sqrt(sqrt(S[0]) * sqrt(S[1]));
    double loss = sm[0] + S[2] + S[3] - 2.0 * scale * S[4];
    out[0] = (float)(loss / 512.0);
  }
}

extern "C" void kernel_launch(void* const* d_in, const int* in_sizes, int n_in,
                              void* d_out, int out_size, void* d_ws, size_t ws_size,
                              hipStream_t stream) {
  const float* X = (const float*)d_in[0];
  const float* Xt = (const float*)d_in[1];
  char* wsb = (char*)d_ws;
  float* Mv = (float*)wsb;
  double* S = (double*)(wsb + 4096);
  float* G = (float*)(wsb + 8192);
  float* big = (float*)(wsb + 8192 + 2 * (size_t)MATF * 4);
  float* Gp = big;                                  // 32 MB, dead after k_gfin
  float* Yb[2] = { big, big + 4 * (size_t)MATF };   // each 4 MB (2 mats x 2 parts)
  float* Zb[2] = { big + 8 * (size_t)MATF, big + 12 * (size_t)MATF };
  float* W = big + 16 * (size_t)MATF;

  hipMemsetAsync(S, 0, 16 * sizeof(double), stream);
  k_means<<<dim3(512, 2), 256, 0, stream>>>(X, Xt, Mv);
  k_gram<<<dim3(10, NK, 2), 256, 0, stream>>>(X, Xt, Gp);
  k_gfin<<<dim3(1024, 2), 256, 0, stream>>>(Gp, Mv, G, S);
  k_nsinit<<<dim3(1024, 2), 256, 0, stream>>>(G, Yb[0], Zb[0], S);
  int cur = 0;
  for (int it = 0; it < 15; ++it) {
    k_ns_W<<<dim3(8, 8, 4), 256, 0, stream>>>(Yb[cur], Zb[cur], W);
    k_ns_YZ<<<dim3(8, 8, 8), 256, 0, stream>>>(Yb[cur], Zb[cur], W, Yb[1 - cur], Zb[1 - cur]);
    cur ^= 1;
  }
  k_cross<<<dim3(256), 256, 0, stream>>>(Yb[cur], S);
  k_final<<<dim3(1), 256, 0, stream>>>(Mv, S, (float*)d_out);
}